// Round 15
// baseline (512.304 us; speedup 1.0000x reference)
//
#include <hip/hip_runtime.h>
#include <math.h>

#define NLAT 64
#define NLON 128
#define MODEL_DIM 66
#define LEARN 64
#define KPL 8
#define KSIZE 7
#define NFREQ 65
#define FPAD 72            // padded spectrum row: 72 float2 = 576 B = 9 lines
#define TOTAL_K 24
#define HEAD_HID 32
#define FFN_HID 128
#define MAXU 20

#define TWO_PI_OVER_N 0.04908738521234052f

typedef unsigned long long u64;

static __device__ __forceinline__ float gelu_f(float v) {
    return 0.5f * v * (1.0f + erff(v * 0.7071067811865475f));
}

// K0 (merged): per-(lvl,k,l) lat nonzero masks. Block per (lvl,kl).
__global__ void k0_mask(const float* __restrict__ psi0, const float* __restrict__ psi1,
                        const float* __restrict__ psi2, u64* __restrict__ nzm3) {
    const int bid = blockIdx.x;         // 1344
    const int lvl = (bid < 448) ? 0 : (bid < 896 ? 1 : 2);
    const int kl = bid - lvl * 448;
    const float* psi = lvl == 0 ? psi0 : (lvl == 1 ? psi1 : psi2);
    const int t = threadIdx.x;          // 256
    const int i = t >> 2, q = t & 3;
    const float4* p = (const float4*)(psi + ((size_t)kl * 64 + i) * NLON + q * 32);
    bool nz = false;
#pragma unroll
    for (int u = 0; u < 8; ++u) {
        const float4 v = p[u];
        nz = nz | (v.x != 0.f) | (v.y != 0.f) | (v.z != 0.f) | (v.w != 0.f);
    }
    __shared__ unsigned char fl[64];
    if (t < 64) fl[t] = 0;
    __syncthreads();
    if (nz) fl[i] = 1;
    __syncthreads();
    if (t == 0) {
        u64 m = 0;
        for (int ii = 0; ii < 64; ++ii) if (fl[ii]) m |= (1ull << ii);
        nzm3[bid] = m;
    }
}

// K1: rfft over lon of the 64 learned channels of x. Xh[ch][i][FPAD].
__global__ void k1_fft_x(const float* __restrict__ x, float2* __restrict__ Xh) {
    const int row = blockIdx.x;        // ch*64 + i
    const int ch = row >> 6;
    const int i = row & 63;
    const int t = threadIdx.x;         // 0..127
    __shared__ float sx[NLON];
    __shared__ float ct[NLON], st[NLON];
    float s, c;
    sincosf(TWO_PI_OVER_N * (float)t, &s, &c);
    ct[t] = c; st[t] = s;
    sx[t] = x[(size_t)(i * NLON + t) * MODEL_DIM + ch];
    __syncthreads();
    if (t < NFREQ) {
        float re = 0.f, im = 0.f;
        for (int p = 0; p < NLON; ++p) {
            const int m = (t * p) & 127;
            const float v = sx[p];
            re = fmaf(v, ct[m], re);
            im = fmaf(-v, st[m], im);
        }
        Xh[(size_t)row * FPAD + t] = make_float2(re, im);
    }
}

// K2 v3: block per (lvl,k,l) — 1344 blocks. Conflict-free [p][f] twiddle
// table in LDS; live rows staged and DFT'd in parallel; dead slots zeroed.
// Pp layout [l][j][k][65], per-level compact stride PS = {8,12,20}.
__global__ __launch_bounds__(256) void k2_dft(
    const float* __restrict__ psi0, const float* __restrict__ psi1,
    const float* __restrict__ psi2, const u64* __restrict__ nzm3,
    float2* __restrict__ Pp3) {
    const int bid = blockIdx.x;            // 1344: lvl*448 + k*64 + l
    const int lvl = bid / 448;
    const int kl = bid - lvl * 448;
    const int k = kl >> 6, l = kl & 63;
    const float* psi = lvl == 0 ? psi0 : (lvl == 1 ? psi1 : psi2);
    const u64* nzm = nzm3 + lvl * 448;
    const int PS = lvl == 0 ? 8 : (lvl == 1 ? 12 : 20);
    float2* Pp = Pp3 + (lvl == 0 ? 0 : (lvl == 1 ? 232960 : 582400))
               + (size_t)l * (PS * KSIZE * NFREQ);
    const int t = threadIdx.x;

    __shared__ float2 tab[NLON * NFREQ];   // [p][f], 66.5 KB
    __shared__ float srow[MAXU * NLON];    // live rows of this k, 10 KB
    __shared__ short rj[MAXU];             // j-slot of live row r
    __shared__ short ri[MAXU];             // lat index of live row r
    __shared__ int cnt_s;
    __shared__ unsigned int livemask_s;

    for (int idx = t; idx < NLON * NFREQ; idx += 256) {
        const int p = idx / NFREQ, f = idx - p * NFREQ;
        float s, c;
        sincosf(TWO_PI_OVER_N * (float)((p * f) & 127), &s, &c);
        tab[idx] = make_float2(c, s);      // conj-rfft: e^{+i theta}
    }
    if (t == 0) {
        const u64 mk = nzm[k * 64 + l];
        u64 uni = 0;
        for (int kk = 0; kk < KSIZE; ++kk) uni |= nzm[kk * 64 + l];
        int j = 0, n = 0;
        unsigned int lm = 0;
        for (u64 m = uni; m && j < PS; m &= m - 1, ++j) {
            const int i = __builtin_ctzll(m);
            if ((mk >> i) & 1ull) {
                rj[n] = (short)j; ri[n] = (short)i; ++n;
                lm |= (1u << j);
            }
        }
        cnt_s = n;
        livemask_s = lm;
    }
    __syncthreads();
    const int cnt = cnt_s;
    const unsigned int lm = livemask_s;

    for (int idx = t; idx < cnt * NLON; idx += 256) {
        const int r = idx >> 7, p = idx & 127;
        srow[r * NLON + p] = psi[(((size_t)(k * 64 + l)) * 64 + ri[r]) * NLON + p];
    }
    __syncthreads();

    for (int task = t; task < cnt * NFREQ; task += 256) {
        const int r = task / NFREQ, f = task - r * NFREQ;
        const float* sp = srow + r * NLON;
        float re = 0.f, im = 0.f;
        for (int p = 0; p < NLON; ++p) {
            const float v = sp[p];                 // broadcast (<=2 r's/wave)
            const float2 cs = tab[p * NFREQ + f];  // consecutive addresses
            re = fmaf(v, cs.x, re);
            im = fmaf(v, cs.y, im);
        }
        Pp[((size_t)(rj[r] * KSIZE + k)) * NFREQ + f] = make_float2(re, im);
    }
    for (int task = t; task < PS * NFREQ; task += 256) {
        const int j = task / NFREQ, f = task - j * NFREQ;
        if (!((lm >> j) & 1u))
            Pp[((size_t)(j * KSIZE + k)) * NFREQ + f] = make_float2(0.f, 0.f);
    }
}

// K3 v11: f-split for occupancy. Block = (32 f, 16 ch) = 512 thr; each block
// covers one (l, f-half, ch-quad). sP holds only the block's 32-f slice of
// the psi pack -> LDS lvl2 35.8 KB -> 4 blocks/CU = 8 waves/SIMD (vs 4).
// Inner loop identical to v10 (c-paired, 2-deep j-prefetch).
// In [ch][c][i][FPAD]; Pp [l][j][k][65] (stride UMAX); Out [ch][o][l][FPAD].
template <int CIN, int UMAX>
__global__ __launch_bounds__(512, 8) void k3_contract(
    const float2* __restrict__ Pp, const float2* __restrict__ In,
    const float* __restrict__ w, const float* __restrict__ bias,
    const u64* __restrict__ nzm, float2* __restrict__ Out) {
    __shared__ float2 sP[UMAX * KSIZE * 32];
    const int bid = blockIdx.x;
    const int tx = threadIdx.x;            // 0..31
    const int ty = threadIdx.y;            // 0..15
    const int tid = ty * 32 + tx;

    if (bid >= 8) {
        // ---------- main path ----------
        const int b = bid - 8;             // 0..511
        const int l = ((b & 7) << 3) | ((b >> 3) & 7);   // l in fast bits (r11 best)
        const int fh = (b >> 6) & 1;
        const int chq = b >> 7;            // 0..3
        const int ch = chq * 16 + ty;
        const int f = fh * 32 + tx;
        u64 uni = 0;
#pragma unroll
        for (int k = 0; k < KSIZE; ++k) uni |= nzm[k * 64 + l];
        int U = __popcll(uni);
        if (U > UMAX) U = UMAX;

        // stage this block's 32-f slice of the psi pack
        const float2* PpL = Pp + (size_t)l * (UMAX * KSIZE * NFREQ) + fh * 32;
        const int nstage = U * KSIZE * 32;
        for (int idx = tid; idx < nstage; idx += 512) {
            const int jk = idx >> 5, fo = idx & 31;
            sP[jk * 32 + fo] = PpL[(size_t)jk * NFREQ + fo];
        }
        __syncthreads();

        float2 acc[KPL];
#pragma unroll
        for (int o = 0; o < KPL; ++o) acc[o] = make_float2(0.f, 0.f);

        int c = 0;
        for (; c + 1 < CIN; c += 2) {          // paired c's, 2-deep j-prefetch
            const float2* inC0 = In + ((size_t)(ch * CIN + c) * NLAT) * FPAD + f;
            const float2* inC1 = inC0 + (size_t)NLAT * FPAD;
            float2 zs0[KSIZE], zs1[KSIZE];
#pragma unroll
            for (int k = 0; k < KSIZE; ++k) {
                zs0[k] = make_float2(0.f, 0.f);
                zs1[k] = make_float2(0.f, 0.f);
            }
            u64 m = uni;
            float2 a0, a1, b0, b1;
            {
                const int i0 = __builtin_ctzll(m); m &= m - 1;
                a0 = inC0[(size_t)i0 * FPAD];
                a1 = inC1[(size_t)i0 * FPAD];
            }
            if (U > 1) {
                const int i1 = __builtin_ctzll(m); m &= m - 1;
                b0 = inC0[(size_t)i1 * FPAD];
                b1 = inC1[(size_t)i1 * FPAD];
            }
            int j = 0;
            while (true) {
                float2 t0 = a0, t1 = a1;
                if (j + 2 < U) {
                    const int i2 = __builtin_ctzll(m); m &= m - 1;
                    a0 = inC0[(size_t)i2 * FPAD];
                    a1 = inC1[(size_t)i2 * FPAD];
                }
#pragma unroll
                for (int k = 0; k < KSIZE; ++k) {
                    const float2 pv = sP[(j * KSIZE + k) * 32 + tx];
                    zs0[k].x = fmaf(pv.x, t0.x, fmaf(-pv.y, t0.y, zs0[k].x));
                    zs0[k].y = fmaf(pv.x, t0.y, fmaf(pv.y, t0.x, zs0[k].y));
                    zs1[k].x = fmaf(pv.x, t1.x, fmaf(-pv.y, t1.y, zs1[k].x));
                    zs1[k].y = fmaf(pv.x, t1.y, fmaf(pv.y, t1.x, zs1[k].y));
                }
                if (++j >= U) break;
                t0 = b0; t1 = b1;
                if (j + 2 < U) {
                    const int i2 = __builtin_ctzll(m); m &= m - 1;
                    b0 = inC0[(size_t)i2 * FPAD];
                    b1 = inC1[(size_t)i2 * FPAD];
                }
#pragma unroll
                for (int k = 0; k < KSIZE; ++k) {
                    const float2 pv = sP[(j * KSIZE + k) * 32 + tx];
                    zs0[k].x = fmaf(pv.x, t0.x, fmaf(-pv.y, t0.y, zs0[k].x));
                    zs0[k].y = fmaf(pv.x, t0.y, fmaf(pv.y, t0.x, zs0[k].y));
                    zs1[k].x = fmaf(pv.x, t1.x, fmaf(-pv.y, t1.y, zs1[k].x));
                    zs1[k].y = fmaf(pv.x, t1.y, fmaf(pv.y, t1.x, zs1[k].y));
                }
                if (++j >= U) break;
            }
#pragma unroll
            for (int o = 0; o < KPL; ++o)
#pragma unroll
                for (int k = 0; k < KSIZE; ++k) {
                    const float wv0 = w[(o * CIN + c) * KSIZE + k];
                    const float wv1 = w[(o * CIN + c + 1) * KSIZE + k];
                    acc[o].x = fmaf(wv0, zs0[k].x, acc[o].x);
                    acc[o].y = fmaf(wv0, zs0[k].y, acc[o].y);
                    acc[o].x = fmaf(wv1, zs1[k].x, acc[o].x);
                    acc[o].y = fmaf(wv1, zs1[k].y, acc[o].y);
                }
        }
        for (; c < CIN; ++c) {                 // remainder (CIN=1)
            const float2* inC = In + ((size_t)(ch * CIN + c) * NLAT) * FPAD + f;
            float2 zs[KSIZE];
#pragma unroll
            for (int k = 0; k < KSIZE; ++k) zs[k] = make_float2(0.f, 0.f);
            u64 m = uni;
            int i = __builtin_ctzll(m); m &= m - 1;
            float2 xv = inC[(size_t)i * FPAD];
            int j = 0;
            while (true) {
                float2 xn;
                const bool more = (j + 1 < U);
                if (more) {
                    i = __builtin_ctzll(m); m &= m - 1;
                    xn = inC[(size_t)i * FPAD];
                }
#pragma unroll
                for (int k = 0; k < KSIZE; ++k) {
                    const float2 pv = sP[(j * KSIZE + k) * 32 + tx];
                    zs[k].x = fmaf(pv.x, xv.x, fmaf(-pv.y, xv.y, zs[k].x));
                    zs[k].y = fmaf(pv.x, xv.y, fmaf(pv.y, xv.x, zs[k].y));
                }
                ++j;
                if (!more) break;
                xv = xn;
            }
#pragma unroll
            for (int o = 0; o < KPL; ++o)
#pragma unroll
                for (int k = 0; k < KSIZE; ++k) {
                    const float wv = w[(o * CIN + c) * KSIZE + k];
                    acc[o].x = fmaf(wv, zs[k].x, acc[o].x);
                    acc[o].y = fmaf(wv, zs[k].y, acc[o].y);
                }
        }
#pragma unroll
        for (int o = 0; o < KPL; ++o) {
            float2 v = acc[o];
            if (f == 0) v.x += 128.0f * bias[o];   // spatial bias == DC-bin offset
            Out[((size_t)(ch * KPL + o) * NLAT + l) * FPAD + f] = v;
        }
    } else {
        // ---------- Nyquist path: f=64; wave = one l; lane = ch ----------
        const int lane = tid & 63;             // ch
        const int wv = tid >> 6;               // 0..7
        const int l = bid * 8 + wv;
        const int ch = lane;
        u64 uni = 0;
#pragma unroll
        for (int k = 0; k < KSIZE; ++k) uni |= nzm[k * 64 + l];
        int U = __popcll(uni);
        if (U > UMAX) U = UMAX;

        const float2* PpL = Pp + (size_t)l * (UMAX * KSIZE * NFREQ);
        float2* sN = sP + wv * (UMAX * KSIZE); // per-wave slice
        for (int idx = lane; idx < U * KSIZE; idx += 64)
            sN[idx] = PpL[(size_t)idx * NFREQ + 64];
        __syncthreads();

        float2 acc[KPL];
#pragma unroll
        for (int o = 0; o < KPL; ++o) acc[o] = make_float2(0.f, 0.f);

        for (int c = 0; c < CIN; ++c) {
            const float2* inC = In + ((size_t)(ch * CIN + c) * NLAT) * FPAD + 64;
            float2 zs[KSIZE];
#pragma unroll
            for (int k = 0; k < KSIZE; ++k) zs[k] = make_float2(0.f, 0.f);
            u64 m = uni;
            for (int j = 0; j < U; ++j) {
                const int i = __builtin_ctzll(m); m &= m - 1;
                const float2 xv = inC[(size_t)i * FPAD];
#pragma unroll
                for (int k = 0; k < KSIZE; ++k) {
                    const float2 pv = sN[j * KSIZE + k];
                    zs[k].x = fmaf(pv.x, xv.x, fmaf(-pv.y, xv.y, zs[k].x));
                    zs[k].y = fmaf(pv.x, xv.y, fmaf(pv.y, xv.x, zs[k].y));
                }
            }
#pragma unroll
            for (int o = 0; o < KPL; ++o)
#pragma unroll
                for (int k = 0; k < KSIZE; ++k) {
                    const float wv2 = w[(o * CIN + c) * KSIZE + k];
                    acc[o].x = fmaf(wv2, zs[k].x, acc[o].x);
                    acc[o].y = fmaf(wv2, zs[k].y, acc[o].y);
                }
        }
#pragma unroll
        for (int o = 0; o < KPL; ++o)
            Out[((size_t)(ch * KPL + o) * NLAT + l) * FPAD + 64] = acc[o];
    }
}

// K4 v4: irfft; wave = one (ch,l), lane = p, all 8 o's per thread.
// Nyquist symmetry halves flops; stores are 2x float4 = 32 B contiguous/lane
// into point-major dbuf [l][p][ch][K].
__global__ __launch_bounds__(256, 4) void k4_irfft(const float2* __restrict__ Ch,
                                                   float* __restrict__ dbuf, int lvl) {
    __shared__ float2 tab[64 * 64];    // [f][p]; 32 KB
    const int t = threadIdx.x;         // 256
    for (int idx = t; idx < 64 * 64; idx += 256) {
        const int ff = idx >> 6, p = idx & 63;
        float s, c;
        sincosf(TWO_PI_OVER_N * (float)((ff * p) & 127), &s, &c);
        tab[idx] = make_float2(c, s);
    }
    __syncthreads();
    const int wv = (blockIdx.x << 2) | (t >> 6);   // 0..4095: ch*64+l
    const int ch = wv >> 6, l = wv & 63;
    const int p = t & 63;
    const float2* Rb = Ch + ((size_t)(ch * 8) * NLAT + l) * FPAD;  // o-stride 64*FPAD

    float Se[8], So[8];
#pragma unroll
    for (int o = 0; o < 8; ++o) { Se[o] = 0.f; So[o] = 0.f; }
    for (int ff = 1; ff < 64; ff += 2) {           // odd f -> So
        const float2 cs = tab[(ff << 6) | p];
#pragma unroll
        for (int o = 0; o < 8; ++o) {
            const float2 a = Rb[(size_t)o * (NLAT * FPAD) + ff];
            So[o] = fmaf(a.x, cs.x, So[o]); So[o] = fmaf(-a.y, cs.y, So[o]);
        }
    }
    for (int ff = 2; ff < 64; ff += 2) {           // even f -> Se
        const float2 cs = tab[(ff << 6) | p];
#pragma unroll
        for (int o = 0; o < 8; ++o) {
            const float2 a = Rb[(size_t)o * (NLAT * FPAD) + ff];
            Se[o] = fmaf(a.x, cs.x, Se[o]); Se[o] = fmaf(-a.y, cs.y, Se[o]);
        }
    }
    const float sgp = (p & 1) ? -1.f : 1.f;
    float o0[8], o1[8];
#pragma unroll
    for (int o = 0; o < 8; ++o) {
        const float bb = Rb[(size_t)o * (NLAT * FPAD)].x
                       + sgp * Rb[(size_t)o * (NLAT * FPAD) + 64].x;
        o0[o] = (bb + 2.f * (Se[o] + So[o])) * (1.f / 128.f);
        o1[o] = (bb + 2.f * (Se[o] - So[o])) * (1.f / 128.f);
    }
    float* d0 = dbuf + ((size_t)(l * NLON + p) * 64 + ch) * TOTAL_K + lvl * 8;
    float* d1 = dbuf + ((size_t)(l * NLON + p + 64) * 64 + ch) * TOTAL_K + lvl * 8;
    *(float4*)(d0) = make_float4(o0[0], o0[1], o0[2], o0[3]);
    *(float4*)(d0 + 4) = make_float4(o0[4], o0[5], o0[6], o0[7]);
    *(float4*)(d1) = make_float4(o1[0], o1[1], o1[2], o1[3]);
    *(float4*)(d1 + 4) = make_float4(o1[4], o1[5], o1[6], o1[7]);
}

// K5 v2: register-resident feats, hw1 repacked in LDS as [k][m][n].
// Block = 64 ch x 4 pos; grid = (64 l, 32 p-quads). dbuf point-major.
__global__ __launch_bounds__(256, 6) void k5_head_ffn(
    const float* __restrict__ dbuf, const float* __restrict__ x,
    const float* __restrict__ hw1, const float* __restrict__ hb1,
    const float* __restrict__ hw2, const float* __restrict__ hb2,
    const float* __restrict__ fw0, const float* __restrict__ fb0,
    const float* __restrict__ fw1, const float* __restrict__ fb1,
    float* __restrict__ out) {
    const int l = blockIdx.x;
    const int pq = blockIdx.y;         // 0..31
    const int ch = threadIdx.x;        // 0..63
    const int pos = threadIdx.y;       // 0..3
    const int p = pq * 4 + pos;
    const int n = ch >> 4;
    const int t = pos * 64 + ch;

    __shared__ float shw1[TOTAL_K * HEAD_HID * 4];   // [k][m][n], 12 KB
    __shared__ float shw2[HEAD_HID * 4];             // [m][n]
    __shared__ float sxl2[4][LEARN];
    __shared__ float sh[4][FFN_HID];

    for (int idx = t; idx < TOTAL_K * HEAD_HID * 4; idx += 256) {
        const int nn = idx & 3, mm = (idx >> 2) & 31, kk = idx >> 7;
        shw1[idx] = hw1[(nn * TOTAL_K + kk) * HEAD_HID + mm];
    }
    if (t < HEAD_HID * 4) shw2[t] = hw2[(t & 3) * HEAD_HID + (t >> 2)];
    __syncthreads();

    // feats: 24 contiguous floats
    float fr[TOTAL_K];
    const float* fp = dbuf + ((size_t)(l * NLON + p) * 64 + ch) * TOTAL_K;
#pragma unroll
    for (int q = 0; q < 6; ++q) *(float4*)&fr[q * 4] = *(const float4*)(fp + q * 4);

    float ho = hb2[n];
    for (int m = 0; m < HEAD_HID; ++m) {
        float a = hb1[n * HEAD_HID + m];
#pragma unroll
        for (int k = 0; k < TOTAL_K; ++k)
            a = fmaf(fr[k], shw1[(k * HEAD_HID + m) * 4 + n], a);
        ho = fmaf(gelu_f(a), shw2[m * 4 + n], ho);
    }
    const float v2 = ho + x[(size_t)(l * NLON + p) * MODEL_DIM + ch];
    sxl2[pos][ch] = v2;
    __syncthreads();

    const float sc0 = x[(size_t)(l * NLON + p) * MODEL_DIM + 64];
    const float sc1 = x[(size_t)(l * NLON + p) * MODEL_DIM + 65];

#pragma unroll
    for (int half = 0; half < 2; ++half) {
        const int m = ch + 64 * half;
        float a = fb0[m];
        for (int k = 0; k < LEARN; ++k)
            a = fmaf(sxl2[pos][k], fw0[k * FFN_HID + m], a);
        a = fmaf(sc0, fw0[64 * FFN_HID + m], a);
        a = fmaf(sc1, fw0[65 * FFN_HID + m], a);
        sh[pos][m] = gelu_f(a);
    }
    __syncthreads();

    float a = fb1[ch];
    for (int m = 0; m < FFN_HID; ++m)
        a = fmaf(sh[pos][m], fw1[m * LEARN + ch], a);
    out[(size_t)(l * NLON + p) * MODEL_DIM + ch] = a + v2;
    if (ch < 2) out[(size_t)(l * NLON + p) * MODEL_DIM + 64 + ch] = ch ? sc1 : sc0;
}

extern "C" void kernel_launch(void* const* d_in, const int* in_sizes, int n_in,
                              void* d_out, int out_size, void* d_ws, size_t ws_size,
                              hipStream_t stream) {
    (void)in_sizes; (void)n_in; (void)out_size; (void)ws_size;
    const float* x = (const float*)d_in[0];
    const float* psi[3] = {(const float*)d_in[1], (const float*)d_in[2], (const float*)d_in[3]};
    const float* w[3] = {(const float*)d_in[4], (const float*)d_in[6], (const float*)d_in[8]};
    const float* b[3] = {(const float*)d_in[5], (const float*)d_in[7], (const float*)d_in[9]};
    const float* hw1 = (const float*)d_in[10];
    const float* hb1 = (const float*)d_in[11];
    const float* hw2 = (const float*)d_in[12];
    const float* hb2 = (const float*)d_in[13];
    const float* fw0 = (const float*)d_in[14];
    const float* fb0 = (const float*)d_in[15];
    const float* fw1 = (const float*)d_in[16];
    const float* fb1 = (const float*)d_in[17];
    float* out = (float*)d_out;

    // workspace carve-up (float2 units), ~100 MB total; all offsets 64B-aligned
    float2* Xh = (float2*)d_ws;                 // 64*64*72            = 294912
    float2* Pp3 = Xh + 294912;                  // 64*(8+12+20)*7*65   = 1164800
    float2* bufA = Pp3 + 1164800;               // 64*8*64*72          = 2359296
    float2* bufB = bufA + 2359296;              // 64*8*64*72
    float* dbuf = (float*)(bufB + 2359296);     // 64*128*64*24 floats
    u64* nzm3 = (u64*)(dbuf + (size_t)64 * 128 * 64 * 24);   // 3*448 masks

    k0_mask<<<dim3(1344), dim3(256), 0, stream>>>(psi[0], psi[1], psi[2], nzm3);
    k1_fft_x<<<dim3(64 * 64), dim3(128), 0, stream>>>(x, Xh);
    k2_dft<<<dim3(1344), dim3(256), 0, stream>>>(psi[0], psi[1], psi[2], nzm3, Pp3);

    for (int lvl = 0; lvl < 3; ++lvl) {
        const u64* nzm = nzm3 + lvl * 448;
        const float2* ob;
        if (lvl == 0) {
            k3_contract<1, 8><<<dim3(520), dim3(32, 16), 0, stream>>>(Pp3, Xh, w[0], b[0], nzm, bufA);
            ob = bufA;
        } else if (lvl == 1) {
            k3_contract<8, 12><<<dim3(520), dim3(32, 16), 0, stream>>>(Pp3 + 232960, bufA, w[1], b[1], nzm, bufB);
            ob = bufB;
        } else {
            k3_contract<8, 20><<<dim3(520), dim3(32, 16), 0, stream>>>(Pp3 + 582400, bufB, w[2], b[2], nzm, bufA);
            ob = bufA;
        }
        k4_irfft<<<dim3(1024), dim3(256), 0, stream>>>(ob, dbuf, lvl);
    }

    k5_head_ffn<<<dim3(64, 32), dim3(64, 4), 0, stream>>>(
        dbuf, x, hw1, hb1, hw2, hb2, fw0, fb0, fw1, fb1, out);
}

// Round 16
// 425.869 us; speedup vs baseline: 1.2030x; 1.2030x over previous
//
#include <hip/hip_runtime.h>
#include <math.h>

#define NLAT 64
#define NLON 128
#define MODEL_DIM 66
#define LEARN 64
#define KPL 8
#define KSIZE 7
#define NFREQ 65
#define FPAD 72            // padded spectrum row: 72 float2 = 576 B = 9 lines
#define TOTAL_K 24
#define HEAD_HID 32
#define FFN_HID 128
#define MAXU 20

#define TWO_PI_OVER_N 0.04908738521234052f

typedef unsigned long long u64;

static __device__ __forceinline__ float gelu_f(float v) {
    return 0.5f * v * (1.0f + erff(v * 0.7071067811865475f));
}

// K0 (merged): per-(lvl,k,l) lat nonzero masks. Block per (lvl,kl).
__global__ void k0_mask(const float* __restrict__ psi0, const float* __restrict__ psi1,
                        const float* __restrict__ psi2, u64* __restrict__ nzm3) {
    const int bid = blockIdx.x;         // 1344
    const int lvl = (bid < 448) ? 0 : (bid < 896 ? 1 : 2);
    const int kl = bid - lvl * 448;
    const float* psi = lvl == 0 ? psi0 : (lvl == 1 ? psi1 : psi2);
    const int t = threadIdx.x;          // 256
    const int i = t >> 2, q = t & 3;
    const float4* p = (const float4*)(psi + ((size_t)kl * 64 + i) * NLON + q * 32);
    bool nz = false;
#pragma unroll
    for (int u = 0; u < 8; ++u) {
        const float4 v = p[u];
        nz = nz | (v.x != 0.f) | (v.y != 0.f) | (v.z != 0.f) | (v.w != 0.f);
    }
    __shared__ unsigned char fl[64];
    if (t < 64) fl[t] = 0;
    __syncthreads();
    if (nz) fl[i] = 1;
    __syncthreads();
    if (t == 0) {
        u64 m = 0;
        for (int ii = 0; ii < 64; ++ii) if (fl[ii]) m |= (1ull << ii);
        nzm3[bid] = m;
    }
}

// K1: rfft over lon of the 64 learned channels of x. Xh[ch][i][FPAD].
__global__ void k1_fft_x(const float* __restrict__ x, float2* __restrict__ Xh) {
    const int row = blockIdx.x;        // ch*64 + i
    const int ch = row >> 6;
    const int i = row & 63;
    const int t = threadIdx.x;         // 0..127
    __shared__ float sx[NLON];
    __shared__ float ct[NLON], st[NLON];
    float s, c;
    sincosf(TWO_PI_OVER_N * (float)t, &s, &c);
    ct[t] = c; st[t] = s;
    sx[t] = x[(size_t)(i * NLON + t) * MODEL_DIM + ch];
    __syncthreads();
    if (t < NFREQ) {
        float re = 0.f, im = 0.f;
        for (int p = 0; p < NLON; ++p) {
            const int m = (t * p) & 127;
            const float v = sx[p];
            re = fmaf(v, ct[m], re);
            im = fmaf(-v, st[m], im);
        }
        Xh[(size_t)row * FPAD + t] = make_float2(re, im);
    }
}

// K2 v3: block per (lvl,k,l) — 1344 blocks. Conflict-free [p][f] twiddle
// table in LDS; live rows staged and DFT'd in parallel; dead slots zeroed.
// Pp layout [l][j][k][65], per-level compact stride PS = {8,12,20}.
__global__ __launch_bounds__(256) void k2_dft(
    const float* __restrict__ psi0, const float* __restrict__ psi1,
    const float* __restrict__ psi2, const u64* __restrict__ nzm3,
    float2* __restrict__ Pp3) {
    const int bid = blockIdx.x;            // 1344: lvl*448 + k*64 + l
    const int lvl = bid / 448;
    const int kl = bid - lvl * 448;
    const int k = kl >> 6, l = kl & 63;
    const float* psi = lvl == 0 ? psi0 : (lvl == 1 ? psi1 : psi2);
    const u64* nzm = nzm3 + lvl * 448;
    const int PS = lvl == 0 ? 8 : (lvl == 1 ? 12 : 20);
    float2* Pp = Pp3 + (lvl == 0 ? 0 : (lvl == 1 ? 232960 : 582400))
               + (size_t)l * (PS * KSIZE * NFREQ);
    const int t = threadIdx.x;

    __shared__ float2 tab[NLON * NFREQ];   // [p][f], 66.5 KB
    __shared__ float srow[MAXU * NLON];    // live rows of this k, 10 KB
    __shared__ short rj[MAXU];             // j-slot of live row r
    __shared__ short ri[MAXU];             // lat index of live row r
    __shared__ int cnt_s;
    __shared__ unsigned int livemask_s;

    for (int idx = t; idx < NLON * NFREQ; idx += 256) {
        const int p = idx / NFREQ, f = idx - p * NFREQ;
        float s, c;
        sincosf(TWO_PI_OVER_N * (float)((p * f) & 127), &s, &c);
        tab[idx] = make_float2(c, s);      // conj-rfft: e^{+i theta}
    }
    if (t == 0) {
        const u64 mk = nzm[k * 64 + l];
        u64 uni = 0;
        for (int kk = 0; kk < KSIZE; ++kk) uni |= nzm[kk * 64 + l];
        int j = 0, n = 0;
        unsigned int lm = 0;
        for (u64 m = uni; m && j < PS; m &= m - 1, ++j) {
            const int i = __builtin_ctzll(m);
            if ((mk >> i) & 1ull) {
                rj[n] = (short)j; ri[n] = (short)i; ++n;
                lm |= (1u << j);
            }
        }
        cnt_s = n;
        livemask_s = lm;
    }
    __syncthreads();
    const int cnt = cnt_s;
    const unsigned int lm = livemask_s;

    for (int idx = t; idx < cnt * NLON; idx += 256) {
        const int r = idx >> 7, p = idx & 127;
        srow[r * NLON + p] = psi[(((size_t)(k * 64 + l)) * 64 + ri[r]) * NLON + p];
    }
    __syncthreads();

    for (int task = t; task < cnt * NFREQ; task += 256) {
        const int r = task / NFREQ, f = task - r * NFREQ;
        const float* sp = srow + r * NLON;
        float re = 0.f, im = 0.f;
        for (int p = 0; p < NLON; ++p) {
            const float v = sp[p];                 // broadcast (<=2 r's/wave)
            const float2 cs = tab[p * NFREQ + f];  // consecutive addresses
            re = fmaf(v, cs.x, re);
            im = fmaf(v, cs.y, im);
        }
        Pp[((size_t)(rj[r] * KSIZE + k)) * NFREQ + f] = make_float2(re, im);
    }
    for (int task = t; task < PS * NFREQ; task += 256) {
        const int j = task / NFREQ, f = task - j * NFREQ;
        if (!((lm >> j) & 1u))
            Pp[((size_t)(j * KSIZE + k)) * NFREQ + f] = make_float2(0.f, 0.f);
    }
}

// K3 v12: round-14 v10 base (best measured). CIN=8: c-paired streams with
// 2-deep j-prefetch. CIN=1: batched unconditional column loads with clamped
// indices (all UMAX loads in flight; consumption bounded by uniform j<U —
// no guarded-unroll/uninitialized-reg hazard).
// In [ch][c][i][FPAD]; Pp [l][j][k][65] (stride UMAX); Out [ch][o][l][FPAD].
template <int CIN, int UMAX>
__global__ __launch_bounds__(512, 4) void k3_contract(
    const float2* __restrict__ Pp, const float2* __restrict__ In,
    const float* __restrict__ w, const float* __restrict__ bias,
    const u64* __restrict__ nzm, float2* __restrict__ Out) {
    __shared__ float2 sP[UMAX * KSIZE * NFREQ];
    const int bid = blockIdx.x;
    const int tx = threadIdx.x, ty = threadIdx.y;
    const int tid = ty * 64 + tx;

    if (bid >= 8) {
        // ---------- main path: f = tx, ch = chg*8+ty, one l ----------
        const int b = bid - 8;
        const int l = ((b & 7) << 3) | ((b >> 6) & 7);   // round-11 decode
        const int ch = (((b >> 3) & 7) << 3) + ty;
        const int f = tx;
        u64 uni = 0;
#pragma unroll
        for (int k = 0; k < KSIZE; ++k) uni |= nzm[k * 64 + l];
        int U = __popcll(uni);
        if (U > UMAX) U = UMAX;

        const float2* PpL = Pp + (size_t)l * (UMAX * KSIZE * NFREQ);
        const int nstage = U * (KSIZE * NFREQ);
        for (int idx = tid; idx < nstage; idx += 512) sP[idx] = PpL[idx];
        __syncthreads();

        float2 acc[KPL];
#pragma unroll
        for (int o = 0; o < KPL; ++o) acc[o] = make_float2(0.f, 0.f);

        int c = 0;
        for (; c + 1 < CIN; c += 2) {          // paired c's, 2-deep j-prefetch
            const float2* inC0 = In + ((size_t)(ch * CIN + c) * NLAT) * FPAD + f;
            const float2* inC1 = inC0 + (size_t)NLAT * FPAD;
            float2 zs0[KSIZE], zs1[KSIZE];
#pragma unroll
            for (int k = 0; k < KSIZE; ++k) {
                zs0[k] = make_float2(0.f, 0.f);
                zs1[k] = make_float2(0.f, 0.f);
            }
            u64 m = uni;
            float2 a0, a1, b0, b1;
            {
                const int i0 = __builtin_ctzll(m); m &= m - 1;
                a0 = inC0[(size_t)i0 * FPAD];
                a1 = inC1[(size_t)i0 * FPAD];
            }
            if (U > 1) {
                const int i1 = __builtin_ctzll(m); m &= m - 1;
                b0 = inC0[(size_t)i1 * FPAD];
                b1 = inC1[(size_t)i1 * FPAD];
            }
            int j = 0;
            while (true) {
                float2 t0 = a0, t1 = a1;
                if (j + 2 < U) {
                    const int i2 = __builtin_ctzll(m); m &= m - 1;
                    a0 = inC0[(size_t)i2 * FPAD];
                    a1 = inC1[(size_t)i2 * FPAD];
                }
#pragma unroll
                for (int k = 0; k < KSIZE; ++k) {
                    const float2 pv = sP[(j * KSIZE + k) * NFREQ + f];
                    zs0[k].x = fmaf(pv.x, t0.x, fmaf(-pv.y, t0.y, zs0[k].x));
                    zs0[k].y = fmaf(pv.x, t0.y, fmaf(pv.y, t0.x, zs0[k].y));
                    zs1[k].x = fmaf(pv.x, t1.x, fmaf(-pv.y, t1.y, zs1[k].x));
                    zs1[k].y = fmaf(pv.x, t1.y, fmaf(pv.y, t1.x, zs1[k].y));
                }
                if (++j >= U) break;
                t0 = b0; t1 = b1;
                if (j + 2 < U) {
                    const int i2 = __builtin_ctzll(m); m &= m - 1;
                    b0 = inC0[(size_t)i2 * FPAD];
                    b1 = inC1[(size_t)i2 * FPAD];
                }
#pragma unroll
                for (int k = 0; k < KSIZE; ++k) {
                    const float2 pv = sP[(j * KSIZE + k) * NFREQ + f];
                    zs0[k].x = fmaf(pv.x, t0.x, fmaf(-pv.y, t0.y, zs0[k].x));
                    zs0[k].y = fmaf(pv.x, t0.y, fmaf(pv.y, t0.x, zs0[k].y));
                    zs1[k].x = fmaf(pv.x, t1.x, fmaf(-pv.y, t1.y, zs1[k].x));
                    zs1[k].y = fmaf(pv.x, t1.y, fmaf(pv.y, t1.x, zs1[k].y));
                }
                if (++j >= U) break;
            }
#pragma unroll
            for (int o = 0; o < KPL; ++o)
#pragma unroll
                for (int k = 0; k < KSIZE; ++k) {
                    const float wv0 = w[(o * CIN + c) * KSIZE + k];
                    const float wv1 = w[(o * CIN + c + 1) * KSIZE + k];
                    acc[o].x = fmaf(wv0, zs0[k].x, acc[o].x);
                    acc[o].y = fmaf(wv0, zs0[k].y, acc[o].y);
                    acc[o].x = fmaf(wv1, zs1[k].x, acc[o].x);
                    acc[o].y = fmaf(wv1, zs1[k].y, acc[o].y);
                }
        }
        for (; c < CIN; ++c) {                 // remainder (CIN=1): batched loads
            const float2* inC = In + ((size_t)(ch * CIN + c) * NLAT) * FPAD + f;
            int ioff[UMAX];
            {
                u64 m2 = uni; int last = 0;
#pragma unroll
                for (int s = 0; s < UMAX; ++s) {
                    if (m2) { last = (int)__builtin_ctzll(m2); m2 &= m2 - 1; }
                    ioff[s] = last;            // clamped: always a valid lat index
                }
            }
            float2 xq[UMAX];
#pragma unroll
            for (int s = 0; s < UMAX; ++s)     // ALL loads unconditional, in flight
                xq[s] = inC[(size_t)ioff[s] * FPAD];
            float2 zs[KSIZE];
#pragma unroll
            for (int k = 0; k < KSIZE; ++k) zs[k] = make_float2(0.f, 0.f);
#pragma unroll
            for (int j = 0; j < UMAX; ++j) {
                if (j >= U) break;             // wave-uniform early exit
                const float2 xv = xq[j];
#pragma unroll
                for (int k = 0; k < KSIZE; ++k) {
                    const float2 pv = sP[(j * KSIZE + k) * NFREQ + f];
                    zs[k].x = fmaf(pv.x, xv.x, fmaf(-pv.y, xv.y, zs[k].x));
                    zs[k].y = fmaf(pv.x, xv.y, fmaf(pv.y, xv.x, zs[k].y));
                }
            }
#pragma unroll
            for (int o = 0; o < KPL; ++o)
#pragma unroll
                for (int k = 0; k < KSIZE; ++k) {
                    const float wv = w[(o * CIN + c) * KSIZE + k];
                    acc[o].x = fmaf(wv, zs[k].x, acc[o].x);
                    acc[o].y = fmaf(wv, zs[k].y, acc[o].y);
                }
        }
#pragma unroll
        for (int o = 0; o < KPL; ++o) {
            float2 v = acc[o];
            if (f == 0) v.x += 128.0f * bias[o];   // spatial bias == DC-bin offset
            Out[((size_t)(ch * KPL + o) * NLAT + l) * FPAD + f] = v;
        }
    } else {
        // ---------- Nyquist path: f=64, ch = tx, wave = one l (ty) ----------
        const int l = (bid << 3) + ty;
        const int ch = tx;
        u64 uni = 0;
#pragma unroll
        for (int k = 0; k < KSIZE; ++k) uni |= nzm[k * 64 + l];
        int U = __popcll(uni);
        if (U > UMAX) U = UMAX;

        const float2* PpL = Pp + (size_t)l * (UMAX * KSIZE * NFREQ);
        float2* sN = sP + ty * (UMAX * KSIZE);     // per-wave slice
        for (int idx = tx; idx < U * KSIZE; idx += 64)
            sN[idx] = PpL[(size_t)idx * NFREQ + 64];
        __syncthreads();

        float2 acc[KPL];
#pragma unroll
        for (int o = 0; o < KPL; ++o) acc[o] = make_float2(0.f, 0.f);

        for (int c = 0; c < CIN; ++c) {
            const float2* inC = In + ((size_t)(ch * CIN + c) * NLAT) * FPAD + 64;
            float2 zs[KSIZE];
#pragma unroll
            for (int k = 0; k < KSIZE; ++k) zs[k] = make_float2(0.f, 0.f);
            u64 m = uni;
            for (int j = 0; j < U; ++j) {
                const int i = __builtin_ctzll(m); m &= m - 1;
                const float2 xv = inC[(size_t)i * FPAD];
#pragma unroll
                for (int k = 0; k < KSIZE; ++k) {
                    const float2 pv = sN[j * KSIZE + k];
                    zs[k].x = fmaf(pv.x, xv.x, fmaf(-pv.y, xv.y, zs[k].x));
                    zs[k].y = fmaf(pv.x, xv.y, fmaf(pv.y, xv.x, zs[k].y));
                }
            }
#pragma unroll
            for (int o = 0; o < KPL; ++o)
#pragma unroll
                for (int k = 0; k < KSIZE; ++k) {
                    const float wv = w[(o * CIN + c) * KSIZE + k];
                    acc[o].x = fmaf(wv, zs[k].x, acc[o].x);
                    acc[o].y = fmaf(wv, zs[k].y, acc[o].y);
                }
        }
#pragma unroll
        for (int o = 0; o < KPL; ++o)
            Out[((size_t)(ch * KPL + o) * NLAT + l) * FPAD + 64] = acc[o];
    }
}

// K4 v5: irfft; wave = one (ch,l), lane = p. The Rb spectra reads are
// lane-uniform, so v4 paid 126 serial uniform loads per wave — now the
// wave's 8x65 spectra are staged cooperatively into LDS (9 coalesced rounds,
// all in flight) and compute reads are LDS broadcasts. Nyquist symmetry
// halves flops; stores 2x float4 = 32 B contiguous/lane into point-major
// dbuf [l][p][ch][K].
__global__ __launch_bounds__(256, 3) void k4_irfft(const float2* __restrict__ Ch,
                                                   float* __restrict__ dbuf, int lvl) {
    __shared__ float2 tab[64 * 64];    // [f][p]; 32 KB
    __shared__ float2 spec[4][520];    // per-wave [o][f]; 16.6 KB
    const int t = threadIdx.x;         // 256
    for (int idx = t; idx < 64 * 64; idx += 256) {
        const int ff = idx >> 6, p = idx & 63;
        float s, c;
        sincosf(TWO_PI_OVER_N * (float)((ff * p) & 127), &s, &c);
        tab[idx] = make_float2(c, s);
    }
    const int wvl = t >> 6;                        // wave in block
    const int lane = t & 63;                       // = p
    const int wv = (blockIdx.x << 2) | wvl;        // 0..4095: ch*64+l
    const int ch = wv >> 6, l = wv & 63;
    const float2* Rb = Ch + ((size_t)(ch * 8) * NLAT + l) * FPAD;  // o-stride 64*FPAD
    for (int idx = lane; idx < 520; idx += 64) {
        const int o = idx / 65, ff = idx - o * 65;
        spec[wvl][idx] = Rb[(size_t)o * (NLAT * FPAD) + ff];
    }
    __syncthreads();
    const float2* sp = spec[wvl];

    float Se[8], So[8];
#pragma unroll
    for (int o = 0; o < 8; ++o) { Se[o] = 0.f; So[o] = 0.f; }
    for (int ff = 1; ff < 64; ff += 2) {           // odd f -> So
        const float2 cs = tab[(ff << 6) | lane];
#pragma unroll
        for (int o = 0; o < 8; ++o) {
            const float2 a = sp[o * 65 + ff];
            So[o] = fmaf(a.x, cs.x, So[o]); So[o] = fmaf(-a.y, cs.y, So[o]);
        }
    }
    for (int ff = 2; ff < 64; ff += 2) {           // even f -> Se
        const float2 cs = tab[(ff << 6) | lane];
#pragma unroll
        for (int o = 0; o < 8; ++o) {
            const float2 a = sp[o * 65 + ff];
            Se[o] = fmaf(a.x, cs.x, Se[o]); Se[o] = fmaf(-a.y, cs.y, Se[o]);
        }
    }
    const float sgp = (lane & 1) ? -1.f : 1.f;
    float o0[8], o1[8];
#pragma unroll
    for (int o = 0; o < 8; ++o) {
        const float bb = sp[o * 65].x + sgp * sp[o * 65 + 64].x;
        o0[o] = (bb + 2.f * (Se[o] + So[o])) * (1.f / 128.f);
        o1[o] = (bb + 2.f * (Se[o] - So[o])) * (1.f / 128.f);
    }
    float* d0 = dbuf + ((size_t)(l * NLON + lane) * 64 + ch) * TOTAL_K + lvl * 8;
    float* d1 = dbuf + ((size_t)(l * NLON + lane + 64) * 64 + ch) * TOTAL_K + lvl * 8;
    *(float4*)(d0) = make_float4(o0[0], o0[1], o0[2], o0[3]);
    *(float4*)(d0 + 4) = make_float4(o0[4], o0[5], o0[6], o0[7]);
    *(float4*)(d1) = make_float4(o1[0], o1[1], o1[2], o1[3]);
    *(float4*)(d1 + 4) = make_float4(o1[4], o1[5], o1[6], o1[7]);
}

// K5 v2: register-resident feats, hw1 repacked in LDS as [k][m][n].
// Block = 64 ch x 4 pos; grid = (64 l, 32 p-quads). dbuf point-major.
__global__ __launch_bounds__(256, 6) void k5_head_ffn(
    const float* __restrict__ dbuf, const float* __restrict__ x,
    const float* __restrict__ hw1, const float* __restrict__ hb1,
    const float* __restrict__ hw2, const float* __restrict__ hb2,
    const float* __restrict__ fw0, const float* __restrict__ fb0,
    const float* __restrict__ fw1, const float* __restrict__ fb1,
    float* __restrict__ out) {
    const int l = blockIdx.x;
    const int pq = blockIdx.y;         // 0..31
    const int ch = threadIdx.x;        // 0..63
    const int pos = threadIdx.y;       // 0..3
    const int p = pq * 4 + pos;
    const int n = ch >> 4;
    const int t = pos * 64 + ch;

    __shared__ float shw1[TOTAL_K * HEAD_HID * 4];   // [k][m][n], 12 KB
    __shared__ float shw2[HEAD_HID * 4];             // [m][n]
    __shared__ float sxl2[4][LEARN];
    __shared__ float sh[4][FFN_HID];

    for (int idx = t; idx < TOTAL_K * HEAD_HID * 4; idx += 256) {
        const int nn = idx & 3, mm = (idx >> 2) & 31, kk = idx >> 7;
        shw1[idx] = hw1[(nn * TOTAL_K + kk) * HEAD_HID + mm];
    }
    if (t < HEAD_HID * 4) shw2[t] = hw2[(t & 3) * HEAD_HID + (t >> 2)];
    __syncthreads();

    // feats: 24 contiguous floats
    float fr[TOTAL_K];
    const float* fp = dbuf + ((size_t)(l * NLON + p) * 64 + ch) * TOTAL_K;
#pragma unroll
    for (int q = 0; q < 6; ++q) *(float4*)&fr[q * 4] = *(const float4*)(fp + q * 4);

    float ho = hb2[n];
    for (int m = 0; m < HEAD_HID; ++m) {
        float a = hb1[n * HEAD_HID + m];
#pragma unroll
        for (int k = 0; k < TOTAL_K; ++k)
            a = fmaf(fr[k], shw1[(k * HEAD_HID + m) * 4 + n], a);
        ho = fmaf(gelu_f(a), shw2[m * 4 + n], ho);
    }
    const float v2 = ho + x[(size_t)(l * NLON + p) * MODEL_DIM + ch];
    sxl2[pos][ch] = v2;
    __syncthreads();

    const float sc0 = x[(size_t)(l * NLON + p) * MODEL_DIM + 64];
    const float sc1 = x[(size_t)(l * NLON + p) * MODEL_DIM + 65];

#pragma unroll
    for (int half = 0; half < 2; ++half) {
        const int m = ch + 64 * half;
        float a = fb0[m];
        for (int k = 0; k < LEARN; ++k)
            a = fmaf(sxl2[pos][k], fw0[k * FFN_HID + m], a);
        a = fmaf(sc0, fw0[64 * FFN_HID + m], a);
        a = fmaf(sc1, fw0[65 * FFN_HID + m], a);
        sh[pos][m] = gelu_f(a);
    }
    __syncthreads();

    float a = fb1[ch];
    for (int m = 0; m < FFN_HID; ++m)
        a = fmaf(sh[pos][m], fw1[m * LEARN + ch], a);
    out[(size_t)(l * NLON + p) * MODEL_DIM + ch] = a + v2;
    if (ch < 2) out[(size_t)(l * NLON + p) * MODEL_DIM + 64 + ch] = ch ? sc1 : sc0;
}

extern "C" void kernel_launch(void* const* d_in, const int* in_sizes, int n_in,
                              void* d_out, int out_size, void* d_ws, size_t ws_size,
                              hipStream_t stream) {
    (void)in_sizes; (void)n_in; (void)out_size; (void)ws_size;
    const float* x = (const float*)d_in[0];
    const float* psi[3] = {(const float*)d_in[1], (const float*)d_in[2], (const float*)d_in[3]};
    const float* w[3] = {(const float*)d_in[4], (const float*)d_in[6], (const float*)d_in[8]};
    const float* b[3] = {(const float*)d_in[5], (const float*)d_in[7], (const float*)d_in[9]};
    const float* hw1 = (const float*)d_in[10];
    const float* hb1 = (const float*)d_in[11];
    const float* hw2 = (const float*)d_in[12];
    const float* hb2 = (const float*)d_in[13];
    const float* fw0 = (const float*)d_in[14];
    const float* fb0 = (const float*)d_in[15];
    const float* fw1 = (const float*)d_in[16];
    const float* fb1 = (const float*)d_in[17];
    float* out = (float*)d_out;

    // workspace carve-up (float2 units), ~100 MB total; all offsets 64B-aligned
    float2* Xh = (float2*)d_ws;                 // 64*64*72            = 294912
    float2* Pp3 = Xh + 294912;                  // 64*(8+12+20)*7*65   = 1164800
    float2* bufA = Pp3 + 1164800;               // 64*8*64*72          = 2359296
    float2* bufB = bufA + 2359296;              // 64*8*64*72
    float* dbuf = (float*)(bufB + 2359296);     // 64*128*64*24 floats
    u64* nzm3 = (u64*)(dbuf + (size_t)64 * 128 * 64 * 24);   // 3*448 masks

    k0_mask<<<dim3(1344), dim3(256), 0, stream>>>(psi[0], psi[1], psi[2], nzm3);
    k1_fft_x<<<dim3(64 * 64), dim3(128), 0, stream>>>(x, Xh);
    k2_dft<<<dim3(1344), dim3(256), 0, stream>>>(psi[0], psi[1], psi[2], nzm3, Pp3);

    for (int lvl = 0; lvl < 3; ++lvl) {
        const u64* nzm = nzm3 + lvl * 448;
        const float2* ob;
        if (lvl == 0) {
            k3_contract<1, 8><<<dim3(520), dim3(64, 8), 0, stream>>>(Pp3, Xh, w[0], b[0], nzm, bufA);
            ob = bufA;
        } else if (lvl == 1) {
            k3_contract<8, 12><<<dim3(520), dim3(64, 8), 0, stream>>>(Pp3 + 232960, bufA, w[1], b[1], nzm, bufB);
            ob = bufB;
        } else {
            k3_contract<8, 20><<<dim3(520), dim3(64, 8), 0, stream>>>(Pp3 + 582400, bufB, w[2], b[2], nzm, bufA);
            ob = bufA;
        }
        k4_irfft<<<dim3(1024), dim3(256), 0, stream>>>(ob, dbuf, lvl);
    }

    k5_head_ffn<<<dim3(64, 32), dim3(64, 4), 0, stream>>>(
        dbuf, x, hw1, hb1, hw2, hb2, fw0, fb0, fw1, fb1, out);
}